// Round 1
// baseline (5698.561 us; speedup 1.0000x reference)
//
#include <hip/hip_runtime.h>

#define NN 50000
#define NE 800000
#define DD 128
#define RR 8

// ---------------- count per (dst, relation) + per-relation totals ----------------
__global__ __launch_bounds__(256) void k_count(const int* __restrict__ ei,
                                               const int* __restrict__ et,
                                               float* __restrict__ cnt,
                                               int* __restrict__ rel_cnt)
{
    int e = blockIdx.x * 256 + threadIdx.x;
    int r = -1;
    if (e < NE) {
        r = et[e];
        int dst = ei[NE + e];
        atomicAdd(&cnt[dst * RR + r], 1.0f);
    }
    // wave-aggregated relation totals (8 atomics/wave instead of 64)
    #pragma unroll
    for (int rr = 0; rr < RR; rr++) {
        unsigned long long mask = __ballot(r == rr);
        if (r == rr) {
            int lane = threadIdx.x & 63;
            int leader = __ffsll((long long)mask) - 1;
            if (lane == leader) atomicAdd(&rel_cnt[rr], (int)__popcll(mask));
        }
    }
}

__global__ void k_scan(const int* __restrict__ rel_cnt,
                       int* __restrict__ rel_off, int* __restrict__ rel_fill)
{
    if (threadIdx.x == 0) {
        int acc = 0;
        for (int r = 0; r < RR; r++) { rel_off[r] = acc; rel_fill[r] = acc; acc += rel_cnt[r]; }
        rel_off[RR] = acc;
    }
}

__global__ __launch_bounds__(256) void k_inv(float* __restrict__ cnt)
{
    int i = blockIdx.x * 256 + threadIdx.x;
    if (i < NN * RR) cnt[i] = 1.0f / fmaxf(cnt[i], 1.0f);
}

// ---------------- bucket edges by relation (wave-aggregated positions) ----------------
__global__ __launch_bounds__(256) void k_compact(const int* __restrict__ ei,
                                                 const int* __restrict__ et,
                                                 int* __restrict__ rel_fill,
                                                 int* __restrict__ rel_src,
                                                 int* __restrict__ rel_dst)
{
    int e = blockIdx.x * 256 + threadIdx.x;
    int r = -1, src = 0, dst = 0;
    if (e < NE) { r = et[e]; src = ei[e]; dst = ei[NE + e]; }
    int lane = threadIdx.x & 63;
    int pos = -1;
    #pragma unroll
    for (int rr = 0; rr < RR; rr++) {
        unsigned long long mask = __ballot(r == rr);
        if (r == rr) {
            int leader = __ffsll((long long)mask) - 1;
            int rank = (int)__popcll(mask & ((1ull << lane) - 1ull));
            int base = 0;
            if (lane == leader) base = atomicAdd(&rel_fill[rr], (int)__popcll(mask));
            base = __shfl(base, leader);
            pos = base + rank;
        }
    }
    if (pos >= 0) { rel_src[pos] = src; rel_dst[pos] = dst; }
}

// ---------------- fp32 tiled GEMM: out[n][c] = (relu?) in[n][:] @ M + bias ----------------
// 64 rows/block, 256 threads, K split into 2 chunks of 64.
// Thread t: row-pair rp = t>>3 (rows 2rp, 2rp+1), colgroup cg = t&7,
// cols c = cg*4 + jj*32 + {0..3}  (jj=0..3) -> conflict-free ds_read_b128 of W.
__global__ __launch_bounds__(256) void k_gemm(const float* __restrict__ in,
                                              const float* __restrict__ M,
                                              const float* __restrict__ bias,
                                              float* __restrict__ out,
                                              int nrows, int relu_in)
{
    __shared__ float Ws[64 * 128];   // 32 KB (one K-chunk of W)
    __shared__ float Is[64 * 66];    // 16.9 KB, stride 66 breaks bank aliasing
    const int t = threadIdx.x;
    const int grow0 = blockIdx.x * 64;
    const int rp = t >> 3;
    const int cg = t & 7;

    float4 acc0[4], acc1[4];
    #pragma unroll
    for (int j = 0; j < 4; j++) {
        acc0[j] = float4{0.f, 0.f, 0.f, 0.f};
        acc1[j] = float4{0.f, 0.f, 0.f, 0.f};
    }

    for (int kt = 0; kt < 128; kt += 64) {
        __syncthreads();
        // stage W chunk (64x128 f32, fully coalesced float4)
        {
            const float4* srcp = (const float4*)(M + kt * 128);
            float4* dstp = (float4*)Ws;
            #pragma unroll
            for (int i = 0; i < 8; i++) dstp[t + 256 * i] = srcp[t + 256 * i];
        }
        // stage input chunk (64 rows x 64 k, float2, stride 66)
        {
            int row = t >> 2;
            int sub = t & 3;
            int grow = grow0 + row;
            #pragma unroll
            for (int i = 0; i < 8; i++) {
                int f2 = sub + 4 * i;   // 0..31
                float2 v = {0.f, 0.f};
                if (grow < nrows) v = *(const float2*)(in + (size_t)grow * 128 + kt + f2 * 2);
                if (relu_in) { v.x = fmaxf(v.x, 0.f); v.y = fmaxf(v.y, 0.f); }
                *(float2*)(Is + row * 66 + f2 * 2) = v;
            }
        }
        __syncthreads();
        const float* isr0 = Is + (2 * rp) * 66;
        const float* isr1 = isr0 + 66;
        #pragma unroll 4
        for (int kk = 0; kk < 64; kk++) {
            float a0 = isr0[kk];
            float a1 = isr1[kk];
            #pragma unroll
            for (int jj = 0; jj < 4; jj++) {
                float4 w = *(const float4*)(Ws + kk * 128 + cg * 4 + jj * 32);
                acc0[jj].x += a0 * w.x; acc0[jj].y += a0 * w.y;
                acc0[jj].z += a0 * w.z; acc0[jj].w += a0 * w.w;
                acc1[jj].x += a1 * w.x; acc1[jj].y += a1 * w.y;
                acc1[jj].z += a1 * w.z; acc1[jj].w += a1 * w.w;
            }
        }
    }

    int r0 = grow0 + 2 * rp;
    #pragma unroll
    for (int jj = 0; jj < 4; jj++) {
        int c = cg * 4 + jj * 32;
        float4 b = {0.f, 0.f, 0.f, 0.f};
        if (bias) b = *(const float4*)(bias + c);
        float4 v0 = acc0[jj]; v0.x += b.x; v0.y += b.y; v0.z += b.z; v0.w += b.w;
        float4 v1 = acc1[jj]; v1.x += b.x; v1.y += b.y; v1.z += b.z; v1.w += b.w;
        if (r0 < nrows)     *(float4*)(out + (size_t)r0 * 128 + c) = v0;
        if (r0 + 1 < nrows) *(float4*)(out + (size_t)(r0 + 1) * 128 + c) = v1;
    }
}

// ---------------- scatter: out[dst] += Y[src] * inv_cnt[dst][r] ----------------
// Grid-stride; edge count for relation r read from device (rel_off).
__global__ __launch_bounds__(256) void k_scatter(const float* __restrict__ Y,
                                                 const int* __restrict__ rel_src,
                                                 const int* __restrict__ rel_dst,
                                                 const int* __restrict__ rel_off,
                                                 int r,
                                                 const float* __restrict__ inv_cnt,
                                                 float* __restrict__ out)
{
    int begin = rel_off[r];
    int n = rel_off[r + 1] - begin;
    long long total = (long long)n * 32;
    for (long long t = (long long)blockIdx.x * 256 + threadIdx.x; t < total;
         t += (long long)gridDim.x * 256) {
        int e = (int)(t >> 5);
        int c = ((int)t & 31) << 2;
        int src = rel_src[begin + e];
        int dst = rel_dst[begin + e];
        float inv = inv_cnt[dst * RR + r];
        float4 v = *(const float4*)(Y + (size_t)src * 128 + c);
        float* o = out + (size_t)dst * 128 + c;
        atomicAdd(o + 0, v.x * inv);
        atomicAdd(o + 1, v.y * inv);
        atomicAdd(o + 2, v.z * inv);
        atomicAdd(o + 3, v.w * inv);
    }
}

// ---------------- row-wise L2 normalize (one wave per row) ----------------
__global__ __launch_bounds__(256) void k_normalize(float* __restrict__ out, int nrows)
{
    int row = blockIdx.x * 4 + (threadIdx.x >> 6);
    if (row >= nrows) return;
    int lane = threadIdx.x & 63;
    float2 v = *(float2*)(out + (size_t)row * 128 + lane * 2);
    float ss = v.x * v.x + v.y * v.y;
    #pragma unroll
    for (int o = 32; o > 0; o >>= 1) ss += __shfl_xor(ss, o);
    float inv = 1.0f / fmaxf(sqrtf(ss), 1e-12f);
    v.x *= inv; v.y *= inv;
    *(float2*)(out + (size_t)row * 128 + lane * 2) = v;
}

extern "C" void kernel_launch(void* const* d_in, const int* in_sizes, int n_in,
                              void* d_out, int out_size, void* d_ws, size_t ws_size,
                              hipStream_t stream)
{
    const float* x     = (const float*)d_in[0];
    const int*   ei    = (const int*)d_in[1];   // [2, E]
    const int*   et    = (const int*)d_in[2];   // [E]
    const float* W1    = (const float*)d_in[3];
    const float* root1 = (const float*)d_in[4];
    const float* b1    = (const float*)d_in[5];
    const float* W2    = (const float*)d_in[6];
    const float* root2 = (const float*)d_in[7];
    const float* b2    = (const float*)d_in[8];
    float* out = (float*)d_out;

    char* ws = (char*)d_ws;
    float* cnt      = (float*)ws;                                  // N*R f32 -> becomes inv_cnt
    int*   meta     = (int*)(ws + (size_t)NN * RR * 4);            // rel_cnt[8] rel_off[9] rel_fill[8]
    int*   rel_cnt  = meta;
    int*   rel_off  = meta + 8;
    int*   rel_fill = meta + 17;
    float* h        = (float*)(ws + (size_t)NN * RR * 4 + 128);    // N*D
    float* Y        = h + (size_t)NN * DD;                         // N*D
    int*   rel_src  = (int*)(Y + (size_t)NN * DD);                 // E
    int*   rel_dst  = rel_src + NE;                                // E

    // zero cnt + rel_cnt
    hipMemsetAsync(cnt, 0, (size_t)NN * RR * 4 + 8 * 4, stream);

    k_count<<<(NE + 255) / 256, 256, 0, stream>>>(ei, et, cnt, rel_cnt);
    k_scan<<<1, 64, 0, stream>>>(rel_cnt, rel_off, rel_fill);
    k_inv<<<(NN * RR + 255) / 256, 256, 0, stream>>>(cnt);
    k_compact<<<(NE + 255) / 256, 256, 0, stream>>>(ei, et, rel_fill, rel_src, rel_dst);

    int gemm_grid = (NN + 63) / 64;

    // ---- layer 1: h = x@root1 + b1 + sum_r mean_r(x@W1r) ----
    k_gemm<<<gemm_grid, 256, 0, stream>>>(x, root1, b1, h, NN, 0);
    for (int r = 0; r < RR; r++) {
        k_gemm<<<gemm_grid, 256, 0, stream>>>(x, W1 + (size_t)r * DD * DD, nullptr, Y, NN, 0);
        k_scatter<<<2048, 256, 0, stream>>>(Y, rel_src, rel_dst, rel_off, r, cnt, h);
    }

    // ---- layer 2 (relu fused into GEMM input loads): out = relu(h)@root2 + b2 + ... ----
    k_gemm<<<gemm_grid, 256, 0, stream>>>(h, root2, b2, out, NN, 1);
    for (int r = 0; r < RR; r++) {
        k_gemm<<<gemm_grid, 256, 0, stream>>>(h, W2 + (size_t)r * DD * DD, nullptr, Y, NN, 1);
        k_scatter<<<2048, 256, 0, stream>>>(Y, rel_src, rel_dst, rel_off, r, cnt, out);
    }

    k_normalize<<<(NN + 3) / 4, 256, 0, stream>>>(out, NN);
}

// Round 2
// 5687.597 us; speedup vs baseline: 1.0019x; 1.0019x over previous
//
#include <hip/hip_runtime.h>

#define NN 50000
#define NE 800000
#define DD 128
#define RR 8

// hardware f32 atomic add (avoids HIP's default CAS-loop lowering for atomicAdd(float*))
__device__ __forceinline__ void atomic_fadd_hw(float* p, float v)
{
    asm volatile("global_atomic_add_f32 %0, %1, off" : : "v"(p), "v"(v) : "memory");
}

// ---------------- count per (dst, relation) + per-relation totals ----------------
__global__ __launch_bounds__(256) void k_count(const int* __restrict__ ei,
                                               const int* __restrict__ et,
                                               int* __restrict__ cnt,
                                               int* __restrict__ rel_cnt)
{
    int e = blockIdx.x * 256 + threadIdx.x;
    int r = -1;
    if (e < NE) {
        r = et[e];
        int dst = ei[NE + e];
        atomicAdd(&cnt[dst * RR + r], 1);   // int atomic: native global_atomic_add
    }
    // wave-aggregated relation totals (8 atomics/wave instead of 64)
    #pragma unroll
    for (int rr = 0; rr < RR; rr++) {
        unsigned long long mask = __ballot(r == rr);
        if (r == rr) {
            int lane = threadIdx.x & 63;
            int leader = __ffsll((long long)mask) - 1;
            if (lane == leader) atomicAdd(&rel_cnt[rr], (int)__popcll(mask));
        }
    }
}

__global__ void k_scan(const int* __restrict__ rel_cnt,
                       int* __restrict__ rel_off, int* __restrict__ rel_fill)
{
    if (threadIdx.x == 0) {
        int acc = 0;
        for (int r = 0; r < RR; r++) { rel_off[r] = acc; rel_fill[r] = acc; acc += rel_cnt[r]; }
        rel_off[RR] = acc;
    }
}

__global__ __launch_bounds__(256) void k_inv(const int* __restrict__ cnt,
                                             float* __restrict__ inv)
{
    int i = blockIdx.x * 256 + threadIdx.x;
    if (i < NN * RR) inv[i] = 1.0f / fmaxf((float)cnt[i], 1.0f);
}

// ---------------- bucket edges by relation (wave-aggregated positions) ----------------
__global__ __launch_bounds__(256) void k_compact(const int* __restrict__ ei,
                                                 const int* __restrict__ et,
                                                 int* __restrict__ rel_fill,
                                                 int* __restrict__ rel_src,
                                                 int* __restrict__ rel_dst)
{
    int e = blockIdx.x * 256 + threadIdx.x;
    int r = -1, src = 0, dst = 0;
    if (e < NE) { r = et[e]; src = ei[e]; dst = ei[NE + e]; }
    int lane = threadIdx.x & 63;
    int pos = -1;
    #pragma unroll
    for (int rr = 0; rr < RR; rr++) {
        unsigned long long mask = __ballot(r == rr);
        if (r == rr) {
            int leader = __ffsll((long long)mask) - 1;
            int rank = (int)__popcll(mask & ((1ull << lane) - 1ull));
            int base = 0;
            if (lane == leader) base = atomicAdd(&rel_fill[rr], (int)__popcll(mask));
            base = __shfl(base, leader);
            pos = base + rank;
        }
    }
    if (pos >= 0) { rel_src[pos] = src; rel_dst[pos] = dst; }
}

// ---------------- fp32 tiled GEMM: out[n][c] = (relu?) in[n][:] @ M + bias ----------------
__global__ __launch_bounds__(256) void k_gemm(const float* __restrict__ in,
                                              const float* __restrict__ M,
                                              const float* __restrict__ bias,
                                              float* __restrict__ out,
                                              int nrows, int relu_in)
{
    __shared__ float Ws[64 * 128];   // 32 KB (one K-chunk of W)
    __shared__ float Is[64 * 66];    // 16.9 KB, stride 66 breaks bank aliasing
    const int t = threadIdx.x;
    const int grow0 = blockIdx.x * 64;
    const int rp = t >> 3;
    const int cg = t & 7;

    float4 acc0[4], acc1[4];
    #pragma unroll
    for (int j = 0; j < 4; j++) {
        acc0[j] = float4{0.f, 0.f, 0.f, 0.f};
        acc1[j] = float4{0.f, 0.f, 0.f, 0.f};
    }

    for (int kt = 0; kt < 128; kt += 64) {
        __syncthreads();
        {
            const float4* srcp = (const float4*)(M + kt * 128);
            float4* dstp = (float4*)Ws;
            #pragma unroll
            for (int i = 0; i < 8; i++) dstp[t + 256 * i] = srcp[t + 256 * i];
        }
        {
            int row = t >> 2;
            int sub = t & 3;
            int grow = grow0 + row;
            #pragma unroll
            for (int i = 0; i < 8; i++) {
                int f2 = sub + 4 * i;   // 0..31
                float2 v = {0.f, 0.f};
                if (grow < nrows) v = *(const float2*)(in + (size_t)grow * 128 + kt + f2 * 2);
                if (relu_in) { v.x = fmaxf(v.x, 0.f); v.y = fmaxf(v.y, 0.f); }
                *(float2*)(Is + row * 66 + f2 * 2) = v;
            }
        }
        __syncthreads();
        const float* isr0 = Is + (2 * rp) * 66;
        const float* isr1 = isr0 + 66;
        #pragma unroll 4
        for (int kk = 0; kk < 64; kk++) {
            float a0 = isr0[kk];
            float a1 = isr1[kk];
            #pragma unroll
            for (int jj = 0; jj < 4; jj++) {
                float4 w = *(const float4*)(Ws + kk * 128 + cg * 4 + jj * 32);
                acc0[jj].x += a0 * w.x; acc0[jj].y += a0 * w.y;
                acc0[jj].z += a0 * w.z; acc0[jj].w += a0 * w.w;
                acc1[jj].x += a1 * w.x; acc1[jj].y += a1 * w.y;
                acc1[jj].z += a1 * w.z; acc1[jj].w += a1 * w.w;
            }
        }
    }

    int r0 = grow0 + 2 * rp;
    #pragma unroll
    for (int jj = 0; jj < 4; jj++) {
        int c = cg * 4 + jj * 32;
        float4 b = {0.f, 0.f, 0.f, 0.f};
        if (bias) b = *(const float4*)(bias + c);
        float4 v0 = acc0[jj]; v0.x += b.x; v0.y += b.y; v0.z += b.z; v0.w += b.w;
        float4 v1 = acc1[jj]; v1.x += b.x; v1.y += b.y; v1.z += b.z; v1.w += b.w;
        if (r0 < nrows)     *(float4*)(out + (size_t)r0 * 128 + c) = v0;
        if (r0 + 1 < nrows) *(float4*)(out + (size_t)(r0 + 1) * 128 + c) = v1;
    }
}

// ---------------- scatter: out[dst] += Y[src] * inv_cnt[dst][r] (hardware f32 atomics) ----------------
__global__ __launch_bounds__(256) void k_scatter(const float* __restrict__ Y,
                                                 const int* __restrict__ rel_src,
                                                 const int* __restrict__ rel_dst,
                                                 const int* __restrict__ rel_off,
                                                 int r,
                                                 const float* __restrict__ inv_cnt,
                                                 float* __restrict__ out)
{
    int begin = rel_off[r];
    int n = rel_off[r + 1] - begin;
    long long total = (long long)n * 32;
    for (long long t = (long long)blockIdx.x * 256 + threadIdx.x; t < total;
         t += (long long)gridDim.x * 256) {
        int e = (int)(t >> 5);
        int c = ((int)t & 31) << 2;
        int src = rel_src[begin + e];
        int dst = rel_dst[begin + e];
        float inv = inv_cnt[dst * RR + r];
        float4 v = *(const float4*)(Y + (size_t)src * 128 + c);
        float* o = out + (size_t)dst * 128 + c;
        atomic_fadd_hw(o + 0, v.x * inv);
        atomic_fadd_hw(o + 1, v.y * inv);
        atomic_fadd_hw(o + 2, v.z * inv);
        atomic_fadd_hw(o + 3, v.w * inv);
    }
}

// ---------------- row-wise L2 normalize (one wave per row) ----------------
__global__ __launch_bounds__(256) void k_normalize(float* __restrict__ out, int nrows)
{
    int row = blockIdx.x * 4 + (threadIdx.x >> 6);
    if (row >= nrows) return;
    int lane = threadIdx.x & 63;
    float2 v = *(float2*)(out + (size_t)row * 128 + lane * 2);
    float ss = v.x * v.x + v.y * v.y;
    #pragma unroll
    for (int o = 32; o > 0; o >>= 1) ss += __shfl_xor(ss, o);
    float inv = 1.0f / fmaxf(sqrtf(ss), 1e-12f);
    v.x *= inv; v.y *= inv;
    *(float2*)(out + (size_t)row * 128 + lane * 2) = v;
}

extern "C" void kernel_launch(void* const* d_in, const int* in_sizes, int n_in,
                              void* d_out, int out_size, void* d_ws, size_t ws_size,
                              hipStream_t stream)
{
    const float* x     = (const float*)d_in[0];
    const int*   ei    = (const int*)d_in[1];   // [2, E]
    const int*   et    = (const int*)d_in[2];   // [E]
    const float* W1    = (const float*)d_in[3];
    const float* root1 = (const float*)d_in[4];
    const float* b1    = (const float*)d_in[5];
    const float* W2    = (const float*)d_in[6];
    const float* root2 = (const float*)d_in[7];
    const float* b2    = (const float*)d_in[8];
    float* out = (float*)d_out;

    char* ws = (char*)d_ws;
    int*   cnt      = (int*)ws;                                    // N*R int
    int*   meta     = (int*)(ws + (size_t)NN * RR * 4);            // rel_cnt[8] rel_off[9] rel_fill[8]
    int*   rel_cnt  = meta;
    int*   rel_off  = meta + 8;
    int*   rel_fill = meta + 17;
    float* inv      = (float*)(ws + (size_t)NN * RR * 4 + 128);    // N*R f32
    float* h        = inv + (size_t)NN * RR;                       // N*D
    float* Y        = h + (size_t)NN * DD;                         // N*D
    int*   rel_src  = (int*)(Y + (size_t)NN * DD);                 // E
    int*   rel_dst  = rel_src + NE;                                // E

    // zero cnt + rel_cnt (contiguous)
    hipMemsetAsync(cnt, 0, (size_t)NN * RR * 4 + 8 * 4, stream);

    k_count<<<(NE + 255) / 256, 256, 0, stream>>>(ei, et, cnt, rel_cnt);
    k_scan<<<1, 64, 0, stream>>>(rel_cnt, rel_off, rel_fill);
    k_inv<<<(NN * RR + 255) / 256, 256, 0, stream>>>(cnt, inv);
    k_compact<<<(NE + 255) / 256, 256, 0, stream>>>(ei, et, rel_fill, rel_src, rel_dst);

    int gemm_grid = (NN + 63) / 64;

    // ---- layer 1: h = x@root1 + b1 + sum_r mean_r(x@W1r) ----
    k_gemm<<<gemm_grid, 256, 0, stream>>>(x, root1, b1, h, NN, 0);
    for (int r = 0; r < RR; r++) {
        k_gemm<<<gemm_grid, 256, 0, stream>>>(x, W1 + (size_t)r * DD * DD, nullptr, Y, NN, 0);
        k_scatter<<<2048, 256, 0, stream>>>(Y, rel_src, rel_dst, rel_off, r, inv, h);
    }

    // ---- layer 2 (relu fused into GEMM input loads) ----
    k_gemm<<<gemm_grid, 256, 0, stream>>>(h, root2, b2, out, NN, 1);
    for (int r = 0; r < RR; r++) {
        k_gemm<<<gemm_grid, 256, 0, stream>>>(h, W2 + (size_t)r * DD * DD, nullptr, Y, NN, 1);
        k_scatter<<<2048, 256, 0, stream>>>(Y, rel_src, rel_dst, rel_off, r, inv, out);
    }

    k_normalize<<<(NN + 3) / 4, 256, 0, stream>>>(out, NN);
}

// Round 3
// 1156.455 us; speedup vs baseline: 4.9276x; 4.9181x over previous
//
#include <hip/hip_runtime.h>

#define NN 50000
#define NE 800000
#define DD 128
#define RR 8
#define MB (NN * RR)          // 400000 buckets keyed by (r, dst)
#define SCAN_BLK 2048         // elements per scan block (256 thr x 8)
#define NBLK ((MB + SCAN_BLK - 1) / SCAN_BLK)   // 196

// ---------------- count per (relation, dst) ----------------
__global__ __launch_bounds__(256) void k_count(const int* __restrict__ ei,
                                               const int* __restrict__ et,
                                               int* __restrict__ cnt)
{
    int e = blockIdx.x * 256 + threadIdx.x;
    if (e < NE) {
        int r = et[e];
        int dst = ei[NE + e];
        atomicAdd(&cnt[r * NN + dst], 1);   // spread over 400k addresses: pipelines fine
    }
}

// ---------------- exclusive scan over cnt -> off (3 kernels) ----------------
__global__ __launch_bounds__(256) void k_scan1(const int* __restrict__ cnt,
                                               int* __restrict__ off,
                                               int* __restrict__ bsum)
{
    __shared__ int lds[256];
    int t = threadIdx.x;
    int base = blockIdx.x * SCAN_BLK + t * 8;
    int v[8], s = 0;
    #pragma unroll
    for (int j = 0; j < 8; j++) {
        int idx = base + j;
        v[j] = (idx < MB) ? cnt[idx] : 0;
        s += v[j];
    }
    lds[t] = s;
    __syncthreads();
    for (int d = 1; d < 256; d <<= 1) {
        int u = (t >= d) ? lds[t - d] : 0;
        __syncthreads();
        lds[t] += u;
        __syncthreads();
    }
    if (t == 255) bsum[blockIdx.x] = lds[255];
    int run = lds[t] - s;   // exclusive prefix of this thread within block
    #pragma unroll
    for (int j = 0; j < 8; j++) {
        int idx = base + j;
        if (idx < MB) off[idx] = run;
        run += v[j];
    }
}

__global__ __launch_bounds__(256) void k_scan2(const int* __restrict__ bsum,
                                               int* __restrict__ carry)
{
    __shared__ int lds[256];
    int t = threadIdx.x;
    int s = (t < NBLK) ? bsum[t] : 0;
    lds[t] = s;
    __syncthreads();
    for (int d = 1; d < 256; d <<= 1) {
        int u = (t >= d) ? lds[t - d] : 0;
        __syncthreads();
        lds[t] += u;
        __syncthreads();
    }
    if (t < NBLK) carry[t] = lds[t] - s;
}

__global__ __launch_bounds__(256) void k_scan3(int* __restrict__ off,
                                               const int* __restrict__ carry)
{
    int c = carry[blockIdx.x];
    int base = blockIdx.x * SCAN_BLK + threadIdx.x * 8;
    #pragma unroll
    for (int j = 0; j < 8; j++) {
        int idx = base + j;
        if (idx < MB) off[idx] += c;
    }
}

// ---------------- place edges into CSR slots ----------------
__global__ __launch_bounds__(256) void k_place(const int* __restrict__ ei,
                                               const int* __restrict__ et,
                                               const int* __restrict__ off,
                                               int* __restrict__ fill,
                                               int* __restrict__ srt_src)
{
    int e = blockIdx.x * 256 + threadIdx.x;
    if (e < NE) {
        int r = et[e];
        int src = ei[e];
        int dst = ei[NE + e];
        int b = r * NN + dst;
        int pos = off[b] + atomicAdd(&fill[b], 1);   // spread atomics
        srt_src[pos] = src;
    }
}

// ---------------- gather-mean per (relation, dst): one wave per dst row ----------------
__global__ __launch_bounds__(256) void k_gather(const float* __restrict__ X,
                                                const int* __restrict__ srt_src,
                                                const int* __restrict__ off,
                                                const int* __restrict__ cnt,
                                                int r,
                                                float* __restrict__ A,
                                                int relu)
{
    int dst = blockIdx.x * 4 + (threadIdx.x >> 6);
    if (dst >= NN) return;
    int lane = threadIdx.x & 63;
    int b = r * NN + dst;
    int s = off[b];
    int c = cnt[b];
    float2 acc = {0.f, 0.f};
    for (int k = 0; k < c; k++) {
        int src = srt_src[s + k];                       // wave-uniform load (broadcast)
        float2 v = *(const float2*)(X + (size_t)src * DD + lane * 2);
        if (relu) { v.x = fmaxf(v.x, 0.f); v.y = fmaxf(v.y, 0.f); }
        acc.x += v.x; acc.y += v.y;
    }
    float inv = 1.0f / (float)max(c, 1);
    acc.x *= inv; acc.y *= inv;
    *(float2*)(A + (size_t)dst * DD + lane * 2) = acc;
}

// ---------------- fp32 tiled GEMM: out[n][:] (+)= (relu?)in[n][:] @ M + bias ----------------
__global__ __launch_bounds__(256) void k_gemm(const float* __restrict__ in,
                                              const float* __restrict__ Mw,
                                              const float* __restrict__ bias,
                                              float* __restrict__ out,
                                              int nrows, int relu_in, int accum)
{
    __shared__ float Ws[64 * 128];   // 32 KB (one K-chunk of W)
    __shared__ float Is[64 * 66];    // stride 66 breaks bank aliasing
    const int t = threadIdx.x;
    const int grow0 = blockIdx.x * 64;
    const int rp = t >> 3;
    const int cg = t & 7;

    float4 acc0[4], acc1[4];
    #pragma unroll
    for (int j = 0; j < 4; j++) {
        acc0[j] = float4{0.f, 0.f, 0.f, 0.f};
        acc1[j] = float4{0.f, 0.f, 0.f, 0.f};
    }

    for (int kt = 0; kt < 128; kt += 64) {
        __syncthreads();
        {
            const float4* srcp = (const float4*)(Mw + kt * 128);
            float4* dstp = (float4*)Ws;
            #pragma unroll
            for (int i = 0; i < 8; i++) dstp[t + 256 * i] = srcp[t + 256 * i];
        }
        {
            int row = t >> 2;
            int sub = t & 3;
            int grow = grow0 + row;
            #pragma unroll
            for (int i = 0; i < 8; i++) {
                int f2 = sub + 4 * i;   // 0..31
                float2 v = {0.f, 0.f};
                if (grow < nrows) v = *(const float2*)(in + (size_t)grow * 128 + kt + f2 * 2);
                if (relu_in) { v.x = fmaxf(v.x, 0.f); v.y = fmaxf(v.y, 0.f); }
                *(float2*)(Is + row * 66 + f2 * 2) = v;
            }
        }
        __syncthreads();
        const float* isr0 = Is + (2 * rp) * 66;
        const float* isr1 = isr0 + 66;
        #pragma unroll 4
        for (int kk = 0; kk < 64; kk++) {
            float a0 = isr0[kk];
            float a1 = isr1[kk];
            #pragma unroll
            for (int jj = 0; jj < 4; jj++) {
                float4 w = *(const float4*)(Ws + kk * 128 + cg * 4 + jj * 32);
                acc0[jj].x += a0 * w.x; acc0[jj].y += a0 * w.y;
                acc0[jj].z += a0 * w.z; acc0[jj].w += a0 * w.w;
                acc1[jj].x += a1 * w.x; acc1[jj].y += a1 * w.y;
                acc1[jj].z += a1 * w.z; acc1[jj].w += a1 * w.w;
            }
        }
    }

    int r0 = grow0 + 2 * rp;
    #pragma unroll
    for (int jj = 0; jj < 4; jj++) {
        int c = cg * 4 + jj * 32;
        float4 b = {0.f, 0.f, 0.f, 0.f};
        if (bias) b = *(const float4*)(bias + c);
        float4 v0 = acc0[jj]; v0.x += b.x; v0.y += b.y; v0.z += b.z; v0.w += b.w;
        float4 v1 = acc1[jj]; v1.x += b.x; v1.y += b.y; v1.z += b.z; v1.w += b.w;
        if (accum) {
            if (r0 < nrows) {
                float4 o = *(const float4*)(out + (size_t)r0 * 128 + c);
                v0.x += o.x; v0.y += o.y; v0.z += o.z; v0.w += o.w;
            }
            if (r0 + 1 < nrows) {
                float4 o = *(const float4*)(out + (size_t)(r0 + 1) * 128 + c);
                v1.x += o.x; v1.y += o.y; v1.z += o.z; v1.w += o.w;
            }
        }
        if (r0 < nrows)     *(float4*)(out + (size_t)r0 * 128 + c) = v0;
        if (r0 + 1 < nrows) *(float4*)(out + (size_t)(r0 + 1) * 128 + c) = v1;
    }
}

// ---------------- row-wise L2 normalize (one wave per row) ----------------
__global__ __launch_bounds__(256) void k_normalize(float* __restrict__ out, int nrows)
{
    int row = blockIdx.x * 4 + (threadIdx.x >> 6);
    if (row >= nrows) return;
    int lane = threadIdx.x & 63;
    float2 v = *(float2*)(out + (size_t)row * 128 + lane * 2);
    float ss = v.x * v.x + v.y * v.y;
    #pragma unroll
    for (int o = 32; o > 0; o >>= 1) ss += __shfl_xor(ss, o);
    float inv = 1.0f / fmaxf(sqrtf(ss), 1e-12f);
    v.x *= inv; v.y *= inv;
    *(float2*)(out + (size_t)row * 128 + lane * 2) = v;
}

extern "C" void kernel_launch(void* const* d_in, const int* in_sizes, int n_in,
                              void* d_out, int out_size, void* d_ws, size_t ws_size,
                              hipStream_t stream)
{
    const float* x     = (const float*)d_in[0];
    const int*   ei    = (const int*)d_in[1];   // [2, E]
    const int*   et    = (const int*)d_in[2];   // [E]
    const float* W1    = (const float*)d_in[3];
    const float* root1 = (const float*)d_in[4];
    const float* b1    = (const float*)d_in[5];
    const float* W2    = (const float*)d_in[6];
    const float* root2 = (const float*)d_in[7];
    const float* b2    = (const float*)d_in[8];
    float* out = (float*)d_out;

    char* ws = (char*)d_ws;
    int*   cnt     = (int*)ws;                       // MB ints
    int*   fill    = cnt + MB;                       // MB ints (adjacent to cnt for one memset)
    int*   off     = fill + MB;                      // MB ints
    int*   bsum    = off + MB;                       // 256 ints
    int*   carry   = bsum + 256;                     // 256 ints
    int*   srt_src = carry + 256;                    // NE ints
    float* h       = (float*)(srt_src + NE);         // N*D f32
    float* A       = h + (size_t)NN * DD;            // N*D f32

    // zero cnt + fill (contiguous)
    hipMemsetAsync(cnt, 0, (size_t)2 * MB * 4, stream);

    k_count<<<(NE + 255) / 256, 256, 0, stream>>>(ei, et, cnt);
    k_scan1<<<NBLK, 256, 0, stream>>>(cnt, off, bsum);
    k_scan2<<<1, 256, 0, stream>>>(bsum, carry);
    k_scan3<<<NBLK, 256, 0, stream>>>(off, carry);
    k_place<<<(NE + 255) / 256, 256, 0, stream>>>(ei, et, off, fill, srt_src);

    int gemm_grid = (NN + 63) / 64;
    int gat_grid = (NN + 3) / 4;

    // ---- layer 1: h = x@root1 + b1 + sum_r mean_r(x) @ W1r ----
    k_gemm<<<gemm_grid, 256, 0, stream>>>(x, root1, b1, h, NN, 0, 0);
    for (int r = 0; r < RR; r++) {
        k_gather<<<gat_grid, 256, 0, stream>>>(x, srt_src, off, cnt, r, A, 0);
        k_gemm<<<gemm_grid, 256, 0, stream>>>(A, W1 + (size_t)r * DD * DD, nullptr, h, NN, 0, 1);
    }

    // ---- layer 2: out = relu(h)@root2 + b2 + sum_r mean_r(relu(h)) @ W2r ----
    k_gemm<<<gemm_grid, 256, 0, stream>>>(h, root2, b2, out, NN, 1, 0);
    for (int r = 0; r < RR; r++) {
        k_gather<<<gat_grid, 256, 0, stream>>>(h, srt_src, off, cnt, r, A, 1);
        k_gemm<<<gemm_grid, 256, 0, stream>>>(A, W2 + (size_t)r * DD * DD, nullptr, out, NN, 0, 1);
    }

    k_normalize<<<gat_grid, 256, 0, stream>>>(out, NN);
}

// Round 4
// 618.965 us; speedup vs baseline: 9.2066x; 1.8684x over previous
//
#include <hip/hip_runtime.h>

#define NN 50000
#define NE 800000
#define DD 128
#define RR 8
#define MB (NN * RR)          // 400000 buckets keyed by (r, dst)
#define SCAN_BLK 2048
#define NBLK ((MB + SCAN_BLK - 1) / SCAN_BLK)   // 196

typedef __attribute__((ext_vector_type(8))) short short8;
typedef __attribute__((ext_vector_type(4))) float f32x4;

__device__ __forceinline__ unsigned short f2bf(float f)
{
    unsigned int u = __float_as_uint(f);
    u = (u + 0x7FFFu + ((u >> 16) & 1u)) >> 16;   // RNE
    return (unsigned short)u;
}
__device__ __forceinline__ float bflo(unsigned int p) { return __uint_as_float(p << 16); }
__device__ __forceinline__ float bfhi(unsigned int p) { return __uint_as_float(p & 0xFFFF0000u); }

// ---------------- count per (relation, dst) ----------------
__global__ __launch_bounds__(256) void k_count(const int* __restrict__ ei,
                                               const int* __restrict__ et,
                                               int* __restrict__ cnt)
{
    int e = blockIdx.x * 256 + threadIdx.x;
    if (e < NE) {
        int r = et[e];
        int dst = ei[NE + e];
        atomicAdd(&cnt[r * NN + dst], 1);
    }
}

// ---------------- exclusive scan over cnt -> off ----------------
__global__ __launch_bounds__(256) void k_scan1(const int* __restrict__ cnt,
                                               int* __restrict__ off,
                                               int* __restrict__ bsum)
{
    __shared__ int lds[256];
    int t = threadIdx.x;
    int base = blockIdx.x * SCAN_BLK + t * 8;
    int v[8], s = 0;
    #pragma unroll
    for (int j = 0; j < 8; j++) {
        int idx = base + j;
        v[j] = (idx < MB) ? cnt[idx] : 0;
        s += v[j];
    }
    lds[t] = s;
    __syncthreads();
    for (int d = 1; d < 256; d <<= 1) {
        int u = (t >= d) ? lds[t - d] : 0;
        __syncthreads();
        lds[t] += u;
        __syncthreads();
    }
    if (t == 255) bsum[blockIdx.x] = lds[255];
    int run = lds[t] - s;
    #pragma unroll
    for (int j = 0; j < 8; j++) {
        int idx = base + j;
        if (idx < MB) off[idx] = run;
        run += v[j];
    }
}

__global__ __launch_bounds__(256) void k_scan2(const int* __restrict__ bsum,
                                               int* __restrict__ carry)
{
    __shared__ int lds[256];
    int t = threadIdx.x;
    int s = (t < NBLK) ? bsum[t] : 0;
    lds[t] = s;
    __syncthreads();
    for (int d = 1; d < 256; d <<= 1) {
        int u = (t >= d) ? lds[t - d] : 0;
        __syncthreads();
        lds[t] += u;
        __syncthreads();
    }
    if (t < NBLK) carry[t] = lds[t] - s;
}

__global__ __launch_bounds__(256) void k_scan3(int* __restrict__ off,
                                               const int* __restrict__ carry)
{
    int c = carry[blockIdx.x];
    int base = blockIdx.x * SCAN_BLK + threadIdx.x * 8;
    #pragma unroll
    for (int j = 0; j < 8; j++) {
        int idx = base + j;
        if (idx < MB) off[idx] += c;
    }
}

// ---------------- place edges into CSR slots ----------------
__global__ __launch_bounds__(256) void k_place(const int* __restrict__ ei,
                                               const int* __restrict__ et,
                                               const int* __restrict__ off,
                                               int* __restrict__ fill,
                                               int* __restrict__ srt_src)
{
    int e = blockIdx.x * 256 + threadIdx.x;
    if (e < NE) {
        int r = et[e];
        int src = ei[e];
        int dst = ei[NE + e];
        int b = r * NN + dst;
        int pos = off[b] + atomicAdd(&fill[b], 1);
        srt_src[pos] = src;
    }
}

// ---------------- f32 -> bf16 convert (vectorized) ----------------
__global__ __launch_bounds__(256) void k_tobf16(const float* __restrict__ x,
                                                unsigned short* __restrict__ xb, int n4)
{
    int i = blockIdx.x * 256 + threadIdx.x;
    if (i < n4) {
        float4 v = ((const float4*)x)[i];
        uint2 o;
        o.x = (unsigned int)f2bf(v.x) | ((unsigned int)f2bf(v.y) << 16);
        o.y = (unsigned int)f2bf(v.z) | ((unsigned int)f2bf(v.w) << 16);
        ((uint2*)xb)[i] = o;
    }
}

// ---------------- weights: transpose + bf16: Wb[m][n][k] = src[m][k][n] ----------------
// m: 0..7 = W1 rel, 8 = root1, 9..16 = W2 rel, 17 = root2
__global__ __launch_bounds__(256) void k_wconv(const float* __restrict__ W1,
                                               const float* __restrict__ root1,
                                               const float* __restrict__ W2,
                                               const float* __restrict__ root2,
                                               unsigned short* __restrict__ Wb)
{
    int e = blockIdx.x * 256 + threadIdx.x;
    if (e >= 18 * 16384) return;
    int m = e >> 14;
    int rem = e & 16383;
    int n = rem >> 7;
    int k = rem & 127;
    float v;
    if (m < 8)       v = W1[m * 16384 + k * 128 + n];
    else if (m == 8) v = root1[k * 128 + n];
    else if (m < 17) v = W2[(m - 9) * 16384 + k * 128 + n];
    else             v = root2[k * 128 + n];
    Wb[e] = f2bf(v);
}

// ---------------- fused layer: out = [A_0..A_7, Xin] @ [W_0..W_7; root] + b ----------------
// 64 dst-rows x 128 cols per block, 4 waves, MFMA 16x16x32 bf16.
// mode 0: +bias, relu, store bf16 to out_bf.  mode 1: +bias, L2-normalize, store f32 to out_f.
__global__ __launch_bounds__(256) void k_layer(const unsigned short* __restrict__ Xin,
                                               const unsigned short* __restrict__ Wb,
                                               const float* __restrict__ bias,
                                               const int* __restrict__ off,
                                               const int* __restrict__ cnt,
                                               const int* __restrict__ srt,
                                               unsigned short* __restrict__ out_bf,
                                               float* __restrict__ out_f,
                                               int mode)
{
    __shared__ unsigned short Wl[128 * 128];   // 32 KB, XOR-swizzled [n][k]
    __shared__ unsigned short Al[64 * 128];    // 16 KB, XOR-swizzled [row][k]
    const int t = threadIdx.x;
    const int w = t >> 6;
    const int lane = t & 63;
    const int grow0 = blockIdx.x * 64;
    const int colb = lane & 15;
    const int hi = lane >> 4;

    f32x4 acc[8];
    #pragma unroll
    for (int tt = 0; tt < 8; tt++) acc[tt] = f32x4{0.f, 0.f, 0.f, 0.f};

    for (int m = 0; m < 9; m++) {
        __syncthreads();   // previous iter's LDS reads done before overwrite
        // ---- stage W_m (transposed [n][k]) into Wl with swizzle ----
        {
            const uint4* wsrc = (const uint4*)(Wb + (size_t)m * 16384);
            #pragma unroll
            for (int c = 0; c < 8; c++) {
                int u = c * 256 + t;           // 16B chunk id, 0..2047
                uint4 v = wsrc[u];
                int n = u >> 4;
                int dstb = (u * 16) ^ ((n & 7) << 4);
                *(uint4*)((char*)Wl + dstb) = v;
            }
        }
        // ---- build A tile ----
        if (m < 8) {
            int rbase = w << 4;
            int bbase = m * NN + grow0 + rbase;
            int offv = 0, cntv = 0;
            if (lane < 16 && grow0 + rbase + lane < NN) {
                offv = off[bbase + lane];
                cntv = cnt[bbase + lane];
            }
            for (int i = 0; i < 16; i++) {
                int row = rbase + i;
                int dstn = grow0 + row;
                unsigned int packed = 0;
                if (dstn < NN) {
                    int s = __shfl(offv, i);
                    int c = __shfl(cntv, i);
                    float ax = 0.f, ay = 0.f;
                    if (c <= 64) {
                        int srcv = (lane < c) ? srt[s + lane] : 0;
                        int k = 0;
                        for (; k + 2 <= c; k += 2) {
                            int s0 = __shfl(srcv, k);
                            int s1 = __shfl(srcv, k + 1);
                            unsigned int p0 = *(const unsigned int*)(Xin + (size_t)s0 * 128 + lane * 2);
                            unsigned int p1 = *(const unsigned int*)(Xin + (size_t)s1 * 128 + lane * 2);
                            ax += bflo(p0) + bflo(p1);
                            ay += bfhi(p0) + bfhi(p1);
                        }
                        if (k < c) {
                            int s0 = __shfl(srcv, k);
                            unsigned int p0 = *(const unsigned int*)(Xin + (size_t)s0 * 128 + lane * 2);
                            ax += bflo(p0);
                            ay += bfhi(p0);
                        }
                    } else {
                        for (int k = 0; k < c; k++) {
                            int s0 = srt[s + k];
                            unsigned int p0 = *(const unsigned int*)(Xin + (size_t)s0 * 128 + lane * 2);
                            ax += bflo(p0);
                            ay += bfhi(p0);
                        }
                    }
                    float invc = 1.0f / (float)(c > 1 ? c : 1);
                    ax *= invc; ay *= invc;
                    packed = (unsigned int)f2bf(ax) | ((unsigned int)f2bf(ay) << 16);
                }
                int byteoff = (row * 256 + lane * 4) ^ ((row & 7) << 4);
                *(unsigned int*)((char*)Al + byteoff) = packed;
            }
        } else {
            // root term: A = Xin rows of this block
            int rbase = w << 4;
            for (int i = 0; i < 16; i++) {
                int row = rbase + i;
                int dstn = grow0 + row;
                unsigned int v = (dstn < NN) ? *(const unsigned int*)(Xin + (size_t)dstn * 128 + lane * 2) : 0u;
                int byteoff = (row * 256 + lane * 4) ^ ((row & 7) << 4);
                *(unsigned int*)((char*)Al + byteoff) = v;
            }
        }
        __syncthreads();
        // ---- MFMA: 4 k-steps x 8 col-tiles ----
        int arow = (w << 4) + colb;
        int aswz = (arow & 7) << 4;
        #pragma unroll
        for (int ks = 0; ks < 4; ks++) {
            int abyte = (arow * 256 + ks * 64 + hi * 16) ^ aswz;
            short8 af = *(const short8*)((const char*)Al + abyte);
            #pragma unroll
            for (int tt = 0; tt < 8; tt++) {
                int n = tt * 16 + colb;
                int bbyte = (n * 256 + ks * 64 + hi * 16) ^ ((n & 7) << 4);
                short8 bfr = *(const short8*)((const char*)Wl + bbyte);
                acc[tt] = __builtin_amdgcn_mfma_f32_16x16x32_bf16(af, bfr, acc[tt], 0, 0, 0);
            }
        }
    }

    // ---- epilogue ----
    if (mode == 0) {
        #pragma unroll
        for (int tt = 0; tt < 8; tt++) {
            float bc = bias[tt * 16 + colb];
            #pragma unroll
            for (int j = 0; j < 4; j++) {
                int row = grow0 + (w << 4) + hi * 4 + j;
                if (row < NN) {
                    float v = fmaxf(acc[tt][j] + bc, 0.f);
                    out_bf[(size_t)row * 128 + tt * 16 + colb] = f2bf(v);
                }
            }
        }
    } else {
        float vv[8][4];
        float ss[4] = {0.f, 0.f, 0.f, 0.f};
        #pragma unroll
        for (int tt = 0; tt < 8; tt++) {
            float bc = bias[tt * 16 + colb];
            #pragma unroll
            for (int j = 0; j < 4; j++) {
                float v = acc[tt][j] + bc;
                vv[tt][j] = v;
                ss[j] += v * v;
            }
        }
        #pragma unroll
        for (int j = 0; j < 4; j++) {
            #pragma unroll
            for (int o = 1; o < 16; o <<= 1) ss[j] += __shfl_xor(ss[j], o);
        }
        float inv[4];
        #pragma unroll
        for (int j = 0; j < 4; j++) inv[j] = 1.0f / fmaxf(sqrtf(ss[j]), 1e-12f);
        #pragma unroll
        for (int tt = 0; tt < 8; tt++) {
            #pragma unroll
            for (int j = 0; j < 4; j++) {
                int row = grow0 + (w << 4) + hi * 4 + j;
                if (row < NN) out_f[(size_t)row * 128 + tt * 16 + colb] = vv[tt][j] * inv[j];
            }
        }
    }
}

extern "C" void kernel_launch(void* const* d_in, const int* in_sizes, int n_in,
                              void* d_out, int out_size, void* d_ws, size_t ws_size,
                              hipStream_t stream)
{
    const float* x     = (const float*)d_in[0];
    const int*   ei    = (const int*)d_in[1];   // [2, E]
    const int*   et    = (const int*)d_in[2];   // [E]
    const float* W1    = (const float*)d_in[3];
    const float* root1 = (const float*)d_in[4];
    const float* b1    = (const float*)d_in[5];
    const float* W2    = (const float*)d_in[6];
    const float* root2 = (const float*)d_in[7];
    const float* b2    = (const float*)d_in[8];
    float* out = (float*)d_out;

    char* ws = (char*)d_ws;
    int* cnt   = (int*)ws;                       // MB
    int* fill  = cnt + MB;                       // MB (adjacent for one memset)
    int* off   = fill + MB;                      // MB
    int* bsum  = off + MB;                       // 256
    int* carry = bsum + 256;                     // 256
    int* srt   = carry + 256;                    // NE
    unsigned short* Xb = (unsigned short*)(srt + NE);       // NN*128
    unsigned short* hb = Xb + (size_t)NN * DD;              // NN*128
    unsigned short* Wb = hb + (size_t)NN * DD;              // 18*16384

    hipMemsetAsync(cnt, 0, (size_t)2 * MB * 4, stream);

    k_count<<<(NE + 255) / 256, 256, 0, stream>>>(ei, et, cnt);
    k_scan1<<<NBLK, 256, 0, stream>>>(cnt, off, bsum);
    k_scan2<<<1, 256, 0, stream>>>(bsum, carry);
    k_scan3<<<NBLK, 256, 0, stream>>>(off, carry);
    k_place<<<(NE + 255) / 256, 256, 0, stream>>>(ei, et, off, fill, srt);

    k_tobf16<<<(NN * DD / 4 + 255) / 256, 256, 0, stream>>>(x, Xb, NN * DD / 4);
    k_wconv<<<(18 * 16384 + 255) / 256, 256, 0, stream>>>(W1, root1, W2, root2, Wb);

    int lay_grid = (NN + 63) / 64;   // 782
    // layer 1: hb = relu(x@root1 + b1 + sum_r mean_r(x)@W1r)  (bf16)
    k_layer<<<lay_grid, 256, 0, stream>>>(Xb, Wb, b1, off, cnt, srt, hb, nullptr, 0);
    // layer 2: out = normalize(hb@root2 + b2 + sum_r mean_r(hb)@W2r)  (f32)
    k_layer<<<lay_grid, 256, 0, stream>>>(hb, Wb + (size_t)9 * 16384, b2, off, cnt, srt, nullptr, out, 1);
}